// Round 14
// baseline (402.597 us; speedup 1.0000x reference)
//
#include <hip/hip_runtime.h>
#include <hip/hip_bf16.h>
#include <stdint.h>

// ---------------------------------------------------------------------------
// ChebConv with attention + per-(t,k) dropout, MI355X bf16 MFMA implementation
// out[b,t,u,o] = relu( sum_k M[t,k] @ x[b,t] @ Theta[k] )   (associativity)
// R14: same K=3072 single GEMM as R13, restructured for CROSS-BLOCK overlap:
// R13 (1 block/CU, 8 lockstep waves) ran LDS pipe (2112cy) and MFMA (1241cy)
// serially (measured 3450cy/chunk). Now 256-thr blocks (4 waves, wave 64x128),
// BK=32, 60KB LDS dbuf -> 2 INDEPENDENT blocks/CU: block A's MFMA covers
// block B's staging (m114 mechanism), no barrier coupling.
// Row padding LDA=40 (banks uniform 2-way) replaces the XOR swizzle.
// mask = threefry2x32 partitionable, key(42), bits = x0^x1   (verified R0)
// ws: M row-major [36][1024][1024] bf16 (75.5MB) | yt [3][12][NR][1024] bf16
// ---------------------------------------------------------------------------

typedef __attribute__((ext_vector_type(8))) short short8;
typedef __attribute__((ext_vector_type(4))) float f32x4;

__device__ __forceinline__ ushort f2bf(float f) {
  __hip_bfloat16 h = __float2bfloat16(f);
  return *reinterpret_cast<ushort*>(&h);
}

__device__ __forceinline__ short8 cvt8(float4 a, float4 b) {
  short8 r;
  r[0] = (short)f2bf(a.x); r[1] = (short)f2bf(a.y);
  r[2] = (short)f2bf(a.z); r[3] = (short)f2bf(a.w);
  r[4] = (short)f2bf(b.x); r[5] = (short)f2bf(b.y);
  r[6] = (short)f2bf(b.z); r[7] = (short)f2bf(b.w);
  return r;
}

__device__ __forceinline__ void threefry2x32(uint32_t c0, uint32_t c1,
                                             uint32_t& o0, uint32_t& o1) {
  const uint32_t ks0 = 0u;
  const uint32_t ks1 = 42u;
  const uint32_t ks2 = ks0 ^ ks1 ^ 0x1BD11BDAu;
  uint32_t x0 = c0 + ks0;
  uint32_t x1 = c1 + ks1;
#define TFR(r) { x0 += x1; x1 = (x1 << (r)) | (x1 >> (32 - (r))); x1 ^= x0; }
  TFR(13) TFR(15) TFR(26) TFR(6)
  x0 += ks1; x1 += ks2 + 1u;
  TFR(17) TFR(29) TFR(16) TFR(24)
  x0 += ks2; x1 += ks0 + 2u;
  TFR(13) TFR(15) TFR(26) TFR(6)
  x0 += ks0; x1 += ks1 + 3u;
  TFR(17) TFR(29) TFR(16) TFR(24)
  x0 += ks1; x1 += ks2 + 4u;
  TFR(13) TFR(15) TFR(26) TFR(6)
  x0 += ks2; x1 += ks0 + 5u;
#undef TFR
  o0 = x0; o1 = x1;
}

// ---------------------------------------------------------------------------
// Kernel 1: build masked M (bf16) row-major padded [36][1024][1024]
// ---------------------------------------------------------------------------
__global__ void build_m(const float* __restrict__ Att,
                        const float* __restrict__ cheb,
                        ushort* __restrict__ Mws) {
  const uint32_t idx = blockIdx.x * 256u + threadIdx.x;
  const uint32_t vp = idx & 1023u;
  const uint32_t up = (idx >> 10) & 1023u;
  const uint32_t tk = idx >> 20;
  float val = 0.f;
  if ((vp < 1000u) & (up < 1000u)) {
    const uint32_t flat = (tk * 1000u + up) * 1000u + vp;
    uint32_t o0, o1;
    threefry2x32(0u, flat, o0, o1);
    const uint32_t bits = o0 ^ o1;
    const float u = __uint_as_float((bits >> 9) | 0x3f800000u) - 1.0f;
    if (u < 0.4f) {
      val = cheb[(tk % 3u) * 1000000u + up * 1000u + vp] *
            Att[up * 1000u + vp] * 2.5f;
    }
  }
  Mws[idx] = f2bf(val);
}

// ---------------------------------------------------------------------------
// Kernel 2: build_yt -- y_k[b,t] = x[b,t] @ Theta_k, stored transposed:
// yt[k][t][nrow=(b-bq0)*64+o][v pad 1024] bf16. (R12/R13-proven)
// ---------------------------------------------------------------------------
#define MFMA(a, b, c) __builtin_amdgcn_mfma_f32_16x16x32_bf16((a), (b), (c), 0, 0, 0)

__global__ __launch_bounds__(192, 1)
void build_yt(const float* __restrict__ x, const float* __restrict__ Theta,
              ushort* __restrict__ yt, int NR, int bq0) {
  __shared__ __align__(16) ushort sm[27648];  // sTh [0,13824) | sY [13824,..)
  const int tid = threadIdx.x, lane = tid & 63, w = tid >> 6;
  const int quad = lane >> 4, l15 = lane & 15;
  const int vh = blockIdx.x, t = blockIdx.y, bb = blockIdx.z;
  const int b = bq0 + bb;

  for (int e = tid; e < 12288; e += 192) {
    const int k = e >> 12, rem = e & 4095, f = rem >> 6, o = rem & 63;
    sm[k * 4608 + o * 72 + f] = f2bf(Theta[e]);
  }
  __syncthreads();

  const ushort* sTh = sm + w * 4608;
  ushort* sY = sm + 13824 + w * 4608;
  const float* xb = x + (((size_t)b * 12 + t) * 1000) * 64;
  const int seg = lane & 7;

#pragma unroll 1
  for (int vi = 0; vi < 8; ++vi) {
    const int vc = vh * 8 + vi;
    const int v0 = vc * 64;

    f32x4 pacc[4][4];
#pragma unroll
    for (int i = 0; i < 4; ++i)
#pragma unroll
      for (int j = 0; j < 4; ++j) pacc[i][j] = f32x4{0.f, 0.f, 0.f, 0.f};

#pragma unroll
    for (int ks = 0; ks < 2; ++ks) {
      short8 av[4], bv[4];
#pragma unroll
      for (int mi = 0; mi < 4; ++mi)
        av[mi] = *(const short8*)&sTh[(mi * 16 + l15) * 72 + ks * 32 + quad * 8];
#pragma unroll
      for (int ni = 0; ni < 4; ++ni) {
        const int v = v0 + ni * 16 + l15;
        float4 c0 = make_float4(0.f, 0.f, 0.f, 0.f);
        float4 c1 = make_float4(0.f, 0.f, 0.f, 0.f);
        if (v < 1000) {
          const float* row = xb + (size_t)v * 64 + ks * 32 + quad * 8;
          c0 = *(const float4*)row;
          c1 = *(const float4*)(row + 4);
        }
        bv[ni] = cvt8(c0, c1);
      }
#pragma unroll
      for (int mi = 0; mi < 4; ++mi)
#pragma unroll
        for (int ni = 0; ni < 4; ++ni)
          pacc[mi][ni] = MFMA(av[mi], bv[ni], pacc[mi][ni]);
    }

#pragma unroll
    for (int mi = 0; mi < 4; ++mi)
#pragma unroll
      for (int ni = 0; ni < 4; ++ni)
#pragma unroll
        for (int r = 0; r < 4; ++r)
          sY[(mi * 16 + quad * 4 + r) * 72 + ni * 16 + l15] = f2bf(pacc[mi][ni][r]);

#pragma unroll
    for (int p = 0; p < 8; ++p) {
      const int o = p * 8 + (lane >> 3);
      const uint4 val = *(const uint4*)&sY[o * 72 + seg * 8];
      *(uint4*)(yt + (((size_t)(w * 12 + t) * (size_t)NR + (size_t)bb * 64 + o) << 10)
                   + v0 + seg * 8) = val;
    }
  }
}

// ---------------------------------------------------------------------------
// Kernel 3: K=3072 GEMM.  256 thr (4 waves, 2x2), block 128u x 256n, wave
// 64u x 128n, K-chunk 32 (96 chunks).  LDS buffer = A[128][40] + B[256][40]
// padded rows (LDA=40 -> uniform 2-way banks, no swizzle); dbuf 60KB ->
// 2 independent blocks/CU.  6 named-reg 16B loads per thread per chunk,
// issue-early / write-late, one __syncthreads per chunk.
// Epilogue: relu + f32 store direct from pacc[4][8].
// ---------------------------------------------------------------------------
#define LDA 40
#define ABUF 5120   // ushorts: 128*40
#define BSEG 2560   // ushorts: 64*40

#define LOADCH(A0, A1, B0, B1, B2, B3, C)                                     \
  do {                                                                        \
    const size_t koA_ = ((size_t)((C) >> 5) << 20) + (size_t)(((C) & 31) * 32); \
    const size_t koB_ = (size_t)((C) >> 5) * ytk + (size_t)(((C) & 31) * 32); \
    A0 = *(const uint4*)(Mws + aA0 + koA_);                                   \
    A1 = *(const uint4*)(Mws + aA1 + koA_);                                   \
    B0 = *(const uint4*)(yt + bB0 + koB_);                                    \
    B1 = *(const uint4*)(yt + bB1 + koB_);                                    \
    B2 = *(const uint4*)(yt + bB2 + koB_);                                    \
    B3 = *(const uint4*)(yt + bB3 + koB_);                                    \
  } while (0)

#define WRITECH(A0, A1, B0, B1, B2, B3, BUF)                                  \
  do {                                                                        \
    *(uint4*)&(BUF)[dA0]             = A0;                                    \
    *(uint4*)&(BUF)[dA0 + BSEG]      = A1;                                    \
    *(uint4*)&(BUF)[dB0]             = B0;                                    \
    *(uint4*)&(BUF)[dB0 + BSEG]      = B1;                                    \
    *(uint4*)&(BUF)[dB0 + 2 * BSEG]  = B2;                                    \
    *(uint4*)&(BUF)[dB0 + 3 * BSEG]  = B3;                                    \
  } while (0)

#define GBURST(BUF)                                                           \
  do {                                                                        \
    const ushort* sAc = (BUF);                                                \
    const ushort* sBc = (BUF) + ABUF;                                         \
    short8 av[4], bv[8];                                                      \
    _Pragma("unroll")                                                         \
    for (int mi = 0; mi < 4; ++mi)                                            \
      av[mi] = *(const short8*)&sAc[(wr * 64 + mi * 16 + l15) * LDA + quad * 8]; \
    _Pragma("unroll")                                                         \
    for (int ni = 0; ni < 8; ++ni)                                            \
      bv[ni] = *(const short8*)&sBc[(wc * 128 + ni * 16 + l15) * LDA + quad * 8]; \
    _Pragma("unroll")                                                         \
    for (int mi = 0; mi < 4; ++mi)                                            \
      _Pragma("unroll")                                                       \
      for (int ni = 0; ni < 8; ++ni)                                          \
        pacc[mi][ni] = MFMA(av[mi], bv[ni], pacc[mi][ni]);                    \
  } while (0)

__global__ __launch_bounds__(256, 2)
void gemm_main(const ushort* __restrict__ Mws, const ushort* __restrict__ yt,
               float* __restrict__ out, int NR, int bq0, int ntcnt) {
  __shared__ __align__(16) ushort smem[30720];  // buf0 | buf1 (15360 each)
  const int tid = threadIdx.x, lane = tid & 63, w = tid >> 6;
  const int wr = w >> 1, wc = w & 1;            // 2 x 2 wave grid
  const int quad = lane >> 4, l15 = lane & 15;

  // XCD-bijective swizzle (gridDim.x % 8 == 0), ut-fastest for B L2-sharing
  const int nb = (int)gridDim.x;
  const int swz = ((int)blockIdx.x & 7) * (nb >> 3) + ((int)blockIdx.x >> 3);
  const int ut = swz & 7;
  const int g = swz >> 3;
  const int nt = g % ntcnt;
  const int t = g / ntcnt;
  const int u0 = ut * 128, n0 = nt * 256;

  ushort* buf0 = smem;
  ushort* buf1 = smem + 15360;

  // staging geometry: thread covers (row = tid>>2, 16B-chunk = tid&3)
  const size_t ytk = (size_t)12 * (size_t)NR * 1024;
  const size_t aA0 = ((size_t)(t * 3) << 20) +
                     ((size_t)(u0 + (tid >> 2)) << 10) + (tid & 3) * 8;
  const size_t aA1 = aA0 + ((size_t)64 << 10);
  const size_t bbase = ((size_t)t * (size_t)NR + n0) << 10;
  const size_t bB0 = bbase + ((size_t)(tid >> 2) << 10) + (tid & 3) * 8;
  const size_t bB1 = bB0 + ((size_t)64 << 10);
  const size_t bB2 = bB0 + ((size_t)128 << 10);
  const size_t bB3 = bB0 + ((size_t)192 << 10);
  const int dA0 = (tid >> 2) * LDA + (tid & 3) * 8;
  const int dB0 = ABUF + (tid >> 2) * LDA + (tid & 3) * 8;

  f32x4 pacc[4][8];
#pragma unroll
  for (int i = 0; i < 4; ++i)
#pragma unroll
    for (int j = 0; j < 8; ++j) pacc[i][j] = f32x4{0.f, 0.f, 0.f, 0.f};

  uint4 pa0, pa1, pb0, pb1, pb2, pb3;
  uint4 qa0, qa1, qb0, qb1, qb2, qb3;

  // prologue: chunk 0 -> buf0
  LOADCH(pa0, pa1, pb0, pb1, pb2, pb3, 0);
  WRITECH(pa0, pa1, pb0, pb1, pb2, pb3, buf0);
  __syncthreads();

#pragma unroll 1
  for (int it = 0; it < 48; ++it) {
    const int c1 = it * 2 + 1;
    // even chunk (buf0): issue c1 loads early, burst, commit c1 -> buf1
    LOADCH(qa0, qa1, qb0, qb1, qb2, qb3, c1);
    __builtin_amdgcn_s_setprio(1);
    GBURST(buf0);
    __builtin_amdgcn_s_setprio(0);
    WRITECH(qa0, qa1, qb0, qb1, qb2, qb3, buf1);
    __syncthreads();
    // odd chunk (buf1): issue c1+1 early, burst, commit -> buf0
    if (c1 < 95) LOADCH(pa0, pa1, pb0, pb1, pb2, pb3, c1 + 1);
    __builtin_amdgcn_s_setprio(1);
    GBURST(buf1);
    __builtin_amdgcn_s_setprio(0);
    if (c1 < 95) WRITECH(pa0, pa1, pb0, pb1, pb2, pb3, buf0);
    __syncthreads();
  }

  // epilogue: relu + f32 store
  const int ubase = u0 + wr * 64;
  const int nbase = n0 + wc * 128;
#pragma unroll
  for (int mi = 0; mi < 4; ++mi)
#pragma unroll
    for (int ni = 0; ni < 8; ++ni) {
      const int n = nbase + ni * 16 + l15;
      const int b = bq0 + (n >> 6), o = n & 63;
      float* op = out + (((size_t)b * 12 + t) * 1000) * 64 + o;
#pragma unroll
      for (int r = 0; r < 4; ++r) {
        const int u = ubase + mi * 16 + quad * 4 + r;
        if (u < 1000) op[(size_t)u * 64] = fmaxf(pacc[mi][ni][r], 0.f);
      }
    }
}

// ---------------------------------------------------------------------------
extern "C" void kernel_launch(void* const* d_in, const int* in_sizes, int n_in,
                              void* d_out, int out_size, void* d_ws, size_t ws_size,
                              hipStream_t stream) {
  const float* x     = (const float*)d_in[0];
  const float* Att   = (const float*)d_in[1];
  const float* cheb  = (const float*)d_in[2];
  const float* Theta = (const float*)d_in[3];
  float* out = (float*)d_out;

  ushort* Mws = (ushort*)d_ws;           // 75.5 MB row-major padded M
  ushort* yt  = Mws + 37748736ull;       // yt region

  build_m<<<147456, 256, 0, stream>>>(Att, cheb, Mws);

  if (ws_size >= 226492416ull) {
    // full path: yt [3][12][2048][1024] bf16 (144MB)
    build_yt<<<dim3(2, 12, 32), 192, 0, stream>>>(x, Theta, yt, 2048, 0);
    gemm_main<<<768, 256, 0, stream>>>(Mws, yt, out, 2048, 0, 8);
  } else {
    // quarter path: 4 passes of 8 batches, yt [3][12][512][1024] (36MB)
    for (int qq = 0; qq < 4; ++qq) {
      build_yt<<<dim3(2, 12, 8), 192, 0, stream>>>(x, Theta, yt, 512, qq * 8);
      gemm_main<<<192, 256, 0, stream>>>(Mws, yt, out, 512, qq * 8, 2);
    }
  }
}

// Round 15
// 283.383 us; speedup vs baseline: 1.4207x; 1.4207x over previous
//
#include <hip/hip_runtime.h>
#include <hip/hip_bf16.h>
#include <stdint.h>

// ---------------------------------------------------------------------------
// ChebConv with attention + per-(t,k) dropout, MI355X bf16 MFMA implementation
// out[b,t,u,o] = relu( sum_k M[t,k] @ (x[b,t] @ Theta[k]) )
// mask = threefry2x32 partitionable, key(42), bits = x0^x1   (verified R0)
// B=32 T=12 V=1000(pad 1024) F=O=64 K=3
// ws: M row-major [36][1024][1024] bf16 (75.5MB) | xt [12][2048][1024] bf16
//     (50.3MB) -- 125.8MB total, fits the proven workspace budget.
//
// R15: cheb_main re-geometried for CROSS-BLOCK overlap: 256 thr / 4 waves
// (2x2 of 32u x 64n), block 64u x 128n, 40KB single-buffer LDS -> 2 blocks/CU
// by BOTH LDS (80KB) and regs (~190 x 2 waves/SIMD <= 512). R8-R14 all ran
// 1 block/CU (512-thr blocks; reg budget) -> LDS pipe and MFMA serialized
// (MfmaUtil pinned 25-33%). Two co-resident independent blocks overlap
// stage and compute (m114). XOR content swizzle (R3-verified, 0 conflicts
// at BK=64; R14's LDA=40 padding gave 2.8e7). Issue-early reg prefetch.
// ---------------------------------------------------------------------------

typedef __attribute__((ext_vector_type(8))) short short8;
typedef __attribute__((ext_vector_type(4))) float f32x4;

__device__ __forceinline__ ushort f2bf(float f) {
  __hip_bfloat16 h = __float2bfloat16(f);
  return *reinterpret_cast<ushort*>(&h);
}

__device__ __forceinline__ void threefry2x32(uint32_t c0, uint32_t c1,
                                             uint32_t& o0, uint32_t& o1) {
  const uint32_t ks0 = 0u;
  const uint32_t ks1 = 42u;
  const uint32_t ks2 = ks0 ^ ks1 ^ 0x1BD11BDAu;
  uint32_t x0 = c0 + ks0;
  uint32_t x1 = c1 + ks1;
#define TFR(r) { x0 += x1; x1 = (x1 << (r)) | (x1 >> (32 - (r))); x1 ^= x0; }
  TFR(13) TFR(15) TFR(26) TFR(6)
  x0 += ks1; x1 += ks2 + 1u;
  TFR(17) TFR(29) TFR(16) TFR(24)
  x0 += ks2; x1 += ks0 + 2u;
  TFR(13) TFR(15) TFR(26) TFR(6)
  x0 += ks0; x1 += ks1 + 3u;
  TFR(17) TFR(29) TFR(16) TFR(24)
  x0 += ks1; x1 += ks2 + 4u;
  TFR(13) TFR(15) TFR(26) TFR(6)
  x0 += ks2; x1 += ks0 + 5u;
#undef TFR
  o0 = x0; o1 = x1;
}

// ---------------------------------------------------------------------------
// Kernel 1: build masked M (bf16) row-major padded [36][1024][1024]
// ---------------------------------------------------------------------------
__global__ void build_m(const float* __restrict__ Att,
                        const float* __restrict__ cheb,
                        ushort* __restrict__ Mws) {
  const uint32_t idx = blockIdx.x * 256u + threadIdx.x;
  const uint32_t vp = idx & 1023u;
  const uint32_t up = (idx >> 10) & 1023u;
  const uint32_t tk = idx >> 20;
  float val = 0.f;
  if ((vp < 1000u) & (up < 1000u)) {
    const uint32_t flat = (tk * 1000u + up) * 1000u + vp;
    uint32_t o0, o1;
    threefry2x32(0u, flat, o0, o1);
    const uint32_t bits = o0 ^ o1;
    const float u = __uint_as_float((bits >> 9) | 0x3f800000u) - 1.0f;
    if (u < 0.4f) {
      val = cheb[(tk % 3u) * 1000000u + up * 1000u + vp] *
            Att[up * 1000u + vp] * 2.5f;
    }
  }
  Mws[idx] = f2bf(val);
}

// ---------------------------------------------------------------------------
// Kernel 2: xt[t][n=b*64+f][v(1024 pad)] bf16  <-  x[b][t][v][f] f32
// ---------------------------------------------------------------------------
__global__ void transpose_x(const float* __restrict__ x,
                            ushort* __restrict__ xt) {
  __shared__ float lt[64][65];
  const int vc = blockIdx.x, t = blockIdx.y, b = blockIdx.z;
  const int tid = threadIdx.x;
  const int v0 = vc * 64;
#pragma unroll
  for (int i = 0; i < 4; ++i) {
    const int c = i * 256 + tid;
    const int vi = c >> 4, f4 = c & 15;
    float4 q = make_float4(0.f, 0.f, 0.f, 0.f);
    if (v0 + vi < 1000)
      q = *(const float4*)(x + ((((size_t)b * 12 + t) * 1000 + v0 + vi) << 6) + f4 * 4);
    lt[f4 * 4 + 0][vi] = q.x;
    lt[f4 * 4 + 1][vi] = q.y;
    lt[f4 * 4 + 2][vi] = q.z;
    lt[f4 * 4 + 3][vi] = q.w;
  }
  __syncthreads();
  const int f = tid >> 2, g = tid & 3;
  alignas(16) ushort tmp[16];
#pragma unroll
  for (int j = 0; j < 16; ++j) tmp[j] = f2bf(lt[f][g * 16 + j]);
  const size_t base = ((size_t)(t * 2048 + b * 64 + f)) << 10;
  *(uint4*)(xt + base + v0 + g * 16)     = *(const uint4*)&tmp[0];
  *(uint4*)(xt + base + v0 + g * 16 + 8) = *(const uint4*)&tmp[8];
}

// ---------------------------------------------------------------------------
// Kernel 3: main fused GEMM.  256 thr (4 waves, 2x2), block 64u x 128n per t,
// wave tile 32u x 64n.  vc-outer (16 chunks of K=64): stage A0|A1|A2 (M_k
// slabs [64][64]) + B (xt [128][64]) = 40KB single buffer; B frags read once
// per wave, 24 MFMA/wave/chunk into pacc[3] (AGPR).  2 blocks/CU overlap.
// Stage 2 (k unrolled): pacc[k] -> sP(bf16) -> oacc += P @ ThetaT[k].
// LDS 40KB: sA 3x4096 @0 | sB 8192 @12288; stage-2: sP = w*2304, sTh @9216.
// Content XOR-swizzle (verified R3): LDS[r][c16B] = G[r][c ^ (r&7)].
// Grid 3072 1D, XCD-bijective, ut-fastest (16 ut-blocks share xt panel in L2).
// ---------------------------------------------------------------------------
#define LDT 72

#define MFMA(a, b, c) __builtin_amdgcn_mfma_f32_16x16x32_bf16((a), (b), (c), 0, 0, 0)

#define LOADCH(R0, R1, R2, R3, R4, R5, R6, R7, R8, R9, VC)                    \
  do {                                                                        \
    const size_t co_ = (size_t)(VC) * 64;                                     \
    R0 = *(const uint4*)(Mws + aS0 + co_);                                    \
    R1 = *(const uint4*)(Mws + aS1 + co_);                                    \
    R2 = *(const uint4*)(Mws + aS2 + co_);                                    \
    R3 = *(const uint4*)(Mws + aS3 + co_);                                    \
    R4 = *(const uint4*)(Mws + aS4 + co_);                                    \
    R5 = *(const uint4*)(Mws + aS5 + co_);                                    \
    R6 = *(const uint4*)(xt + bS0 + co_);                                     \
    R7 = *(const uint4*)(xt + bS1 + co_);                                     \
    R8 = *(const uint4*)(xt + bS2 + co_);                                     \
    R9 = *(const uint4*)(xt + bS3 + co_);                                     \
  } while (0)

#define WRITECH(R0, R1, R2, R3, R4, R5, R6, R7, R8, R9)                       \
  do {                                                                        \
    *(uint4*)&smem[(tid) * 8]                = R0;                            \
    *(uint4*)&smem[(256 + tid) * 8]          = R1;                            \
    *(uint4*)&smem[(512 + tid) * 8]          = R2;                            \
    *(uint4*)&smem[(768 + tid) * 8]          = R3;                            \
    *(uint4*)&smem[(1024 + tid) * 8]         = R4;                            \
    *(uint4*)&smem[(1280 + tid) * 8]         = R5;                            \
    *(uint4*)&smem[12288 + (tid) * 8]        = R6;                            \
    *(uint4*)&smem[12288 + (256 + tid) * 8]  = R7;                            \
    *(uint4*)&smem[12288 + (512 + tid) * 8]  = R8;                            \
    *(uint4*)&smem[12288 + (768 + tid) * 8]  = R9;                            \
  } while (0)

#define BURST()                                                               \
  do {                                                                        \
    _Pragma("unroll")                                                         \
    for (int ks = 0; ks < 2; ++ks) {                                          \
      const int cs_ = (((ks * 4 + quad) ^ rsw)) << 3;                         \
      short8 bv[4];                                                           \
      _Pragma("unroll")                                                       \
      for (int ni = 0; ni < 4; ++ni)                                          \
        bv[ni] = *(const short8*)&smem[12288 +                                \
                     (wn * 64 + ni * 16 + l15) * 64 + cs_];                   \
      _Pragma("unroll")                                                       \
      for (int k = 0; k < 3; ++k) {                                           \
        short8 av[2];                                                         \
        _Pragma("unroll")                                                     \
        for (int mi = 0; mi < 2; ++mi)                                        \
          av[mi] = *(const short8*)&smem[k * 4096 +                           \
                       (wu * 32 + mi * 16 + l15) * 64 + cs_];                 \
        _Pragma("unroll")                                                     \
        for (int mi = 0; mi < 2; ++mi)                                        \
          _Pragma("unroll")                                                   \
          for (int ni = 0; ni < 4; ++ni)                                      \
            pacc[k][mi][ni] = MFMA(av[mi], bv[ni], pacc[k][mi][ni]);          \
      }                                                                       \
    }                                                                         \
  } while (0)

__global__ __launch_bounds__(256, 2)
void cheb_main(const ushort* __restrict__ Mws, const ushort* __restrict__ xt,
               const float* __restrict__ Theta, float* __restrict__ out) {
  __shared__ __align__(16) ushort smem[20480];  // 40 KB
  const int tid = threadIdx.x;
  const int lane = tid & 63;
  const int w = tid >> 6;              // wave 0..3
  const int wu = w >> 1, wn = w & 1;   // wave tile: u = wu*32, n = wn*64
  const int quad = lane >> 4, l15 = lane & 15;
  const int rsw = l15 & 7;

  // XCD-bijective decode (3072 % 8 == 0), ut-fastest within each XCD chunk
  const int bid = blockIdx.x;
  const int swz = (bid & 7) * 384 + (bid >> 3);
  const int ut = swz & 15;
  const int g = swz >> 4;              // 0..191
  const int nt = g & 15;
  const int t = g >> 4;                // 0..11
  const int u0 = ut * 64, n0 = nt * 128;

  const size_t mbase = (size_t)(t * 3) << 20;
  const size_t xrow0 = (size_t)(t * 2048 + n0);

  // staging source bases (content XOR pre-swizzle on 16B chunks)
  const int rA0 = tid >> 3,           cA0 = (tid & 7) ^ (rA0 & 7);
  const int rA1 = (256 + tid) >> 3 & 63, cA1 = (tid & 7) ^ (rA1 & 7);
  const int rA2 = tid >> 3,           cA2 = cA0;   // slab 1, same row/ch map
  const int rA3 = rA1,                cA3 = cA1;
  const int rA4 = tid >> 3,           cA4 = cA0;   // slab 2
  const int rA5 = rA1,                cA5 = cA1;
  const size_t aS0 = mbase + ((size_t)(u0 + rA0) << 10) + cA0 * 8;
  const size_t aS1 = mbase + ((size_t)(u0 + rA1) << 10) + cA1 * 8;
  const size_t aS2 = mbase + (1ull << 20) + ((size_t)(u0 + rA2) << 10) + cA2 * 8;
  const size_t aS3 = mbase + (1ull << 20) + ((size_t)(u0 + rA3) << 10) + cA3 * 8;
  const size_t aS4 = mbase + (2ull << 20) + ((size_t)(u0 + rA4) << 10) + cA4 * 8;
  const size_t aS5 = mbase + (2ull << 20) + ((size_t)(u0 + rA5) << 10) + cA5 * 8;
  const int rB0 = tid >> 3,           cB0 = (tid & 7) ^ (rB0 & 7);
  const int rB1 = (256 + tid) >> 3,   cB1 = (tid & 7) ^ (rB1 & 7);
  const int rB2 = (512 + tid) >> 3,   cB2 = (tid & 7) ^ (rB2 & 7);
  const int rB3 = (768 + tid) >> 3,   cB3 = (tid & 7) ^ (rB3 & 7);
  const size_t bS0 = ((xrow0 + rB0) << 10) + cB0 * 8;
  const size_t bS1 = ((xrow0 + rB1) << 10) + cB1 * 8;
  const size_t bS2 = ((xrow0 + rB2) << 10) + cB2 * 8;
  const size_t bS3 = ((xrow0 + rB3) << 10) + cB3 * 8;

  f32x4 pacc[3][2][4];
#pragma unroll
  for (int k = 0; k < 3; ++k)
#pragma unroll
    for (int i = 0; i < 2; ++i)
#pragma unroll
      for (int j = 0; j < 4; ++j) pacc[k][i][j] = f32x4{0.f, 0.f, 0.f, 0.f};

  uint4 p0, p1, p2, p3, p4, p5, p6, p7, p8, p9;

  // prologue: chunk 0
  LOADCH(p0, p1, p2, p3, p4, p5, p6, p7, p8, p9, 0);
  WRITECH(p0, p1, p2, p3, p4, p5, p6, p7, p8, p9);
  __syncthreads();

#pragma unroll 1
  for (int vc = 0; vc < 16; ++vc) {
    if (vc < 15) LOADCH(p0, p1, p2, p3, p4, p5, p6, p7, p8, p9, vc + 1);
    __builtin_amdgcn_s_setprio(1);
    BURST();
    __builtin_amdgcn_s_setprio(0);
    __syncthreads();               // all waves done reading this chunk
    if (vc < 15) {
      WRITECH(p0, p1, p2, p3, p4, p5, p6, p7, p8, p9);
      __syncthreads();             // next chunk visible
    }
  }

  // ---- stage 2: oacc += P_k @ ThetaT[k], k fully unrolled ----
  ushort* sP  = smem + w * 2304;       // 32 x 72, wave-local (overlays sA)
  ushort* sTh = smem + 9216;           // 64 x 72 (overlays sA/sB boundary)
  f32x4 oacc[2][4];
#pragma unroll
  for (int i = 0; i < 2; ++i)
#pragma unroll
    for (int j = 0; j < 4; ++j) oacc[i][j] = f32x4{0.f, 0.f, 0.f, 0.f};

#pragma unroll
  for (int k = 0; k < 3; ++k) {
    __syncthreads();  // prev readers done
#pragma unroll
    for (int mi = 0; mi < 2; ++mi)
#pragma unroll
      for (int ni = 0; ni < 4; ++ni)
#pragma unroll
        for (int r = 0; r < 4; ++r)
          sP[(mi * 16 + quad * 4 + r) * LDT + ni * 16 + l15] = f2bf(pacc[k][mi][ni][r]);
    for (int e = tid; e < 4096; e += 256) {
      const int f = e >> 6, o = e & 63;
      sTh[o * LDT + f] = f2bf(Theta[k * 4096 + e]);
    }
    __syncthreads();
#pragma unroll
    for (int ks = 0; ks < 2; ++ks) {
      short8 a2[2], b2[4];
#pragma unroll
      for (int mi = 0; mi < 2; ++mi)
        a2[mi] = *(const short8*)&sP[(mi * 16 + l15) * LDT + ks * 32 + quad * 8];
#pragma unroll
      for (int ni = 0; ni < 4; ++ni)
        b2[ni] = *(const short8*)&sTh[(ni * 16 + l15) * LDT + ks * 32 + quad * 8];
#pragma unroll
      for (int mi = 0; mi < 2; ++mi)
#pragma unroll
        for (int ni = 0; ni < 4; ++ni)
          oacc[mi][ni] = MFMA(a2[mi], b2[ni], oacc[mi][ni]);
    }
  }

  // ---- epilogue: relu + store ----
#pragma unroll
  for (int mi = 0; mi < 2; ++mi) {
    const int u_base = u0 + wu * 32 + mi * 16 + quad * 4;
#pragma unroll
    for (int ni = 0; ni < 4; ++ni) {
      const int n = n0 + wn * 64 + ni * 16 + l15;
      const int b = n >> 6, oo = n & 63;
      float* op = out + (((size_t)b * 12 + t) * 1000) * 64 + oo;
#pragma unroll
      for (int r = 0; r < 4; ++r) {
        const int u = u_base + r;
        if (u < 1000) op[(size_t)u * 64] = fmaxf(oacc[mi][ni][r], 0.f);
      }
    }
  }
}

// ---------------------------------------------------------------------------
extern "C" void kernel_launch(void* const* d_in, const int* in_sizes, int n_in,
                              void* d_out, int out_size, void* d_ws, size_t ws_size,
                              hipStream_t stream) {
  const float* x     = (const float*)d_in[0];
  const float* Att   = (const float*)d_in[1];
  const float* cheb  = (const float*)d_in[2];
  const float* Theta = (const float*)d_in[3];
  float* out = (float*)d_out;

  ushort* Mws = (ushort*)d_ws;                 // 36*1024*1024 bf16
  ushort* xtw = Mws + 37748736ull;             // 12*2048*1024 bf16
  // requires ws_size >= 125,829,120 bytes (proven budget)

  build_m<<<147456, 256, 0, stream>>>(Att, cheb, Mws);
  transpose_x<<<dim3(16, 12, 32), 256, 0, stream>>>(x, xtw);
  cheb_main<<<3072, 256, 0, stream>>>(Mws, xtw, Theta, out);
}